// Round 1
// baseline (2016.271 us; speedup 1.0000x reference)
//
#include <hip/hip_runtime.h>

// ---------------------------------------------------------------------------
// ExtraPositionPromptSABottleneck on MI355X (gfx950)
// B=8, DIMS=512, C=256, H=W=64, N=4096.
//
// Pipeline (all intermediates bf16, k-contiguous for the consumer GEMM):
//   transpose_x : x[b,d,n] f32 -> xt[b*n][d] bf16            (A for GEMM1)
//   gemm1       : x1t[n][c]  = silu(bn1(xt @ cv1_w^T))        M=32768 N=256 K=512
//   gemm2       : qkvet[n][j] = x1t @ Wqkve^T + bias          M=32768 N=1024 K=256
//   transpose_v : v part of qkvet -> v_cm[b][c][m]
//   per batch b:
//     gemm3     : S[n][m] = q.k + pos.e                       M=4096 N=4096 K=512
//     softmax   : P = softmax_rows(S)  (bf16)
//     gemm4     : out_t[n][c] = P @ v_cm^T                    M=4096 N=256 K=4096
//   gemm5       : d_out[b][d][n] = x + silu(bn2(W2 @ out_t^T)) M=512 N=4096 K=256
//
// All GEMMs share one MFMA micro-tile: wave computes 64x64 via 4x4 frags of
// v_mfma_f32_16x16x32_bf16; A-frag = A[m=lane&15][k=(lane>>4)*8+j] (b128 load
// from k-contiguous A), B-frag symmetric from B^T-layout [N][K]; D mapping
// col=lane&15, row=(lane>>4)*4+reg (HW-verified layouts per guide §3).
// ---------------------------------------------------------------------------

typedef __bf16 bf16;
typedef __attribute__((ext_vector_type(8))) __bf16 bf16x8;
typedef __attribute__((ext_vector_type(4))) float f32x4;

__device__ __forceinline__ float silu_f(float x) { return x / (1.f + __expf(-x)); }

// Accumulate a 64x64 wave tile: acc += A_tile(64xK) * B_tile(64xK)^T
// A, B already offset to the wave's 64-row origins. lda/ldb in elements.
__device__ __forceinline__ void mfma_tile_accum(
    const bf16* __restrict__ A, int lda,
    const bf16* __restrict__ B, int ldb,
    int K, f32x4 (&acc)[4][4])
{
    const int lane = threadIdx.x & 63;
    const int lm = lane & 15;
    const int kq = lane >> 4;
    const bf16* pa = A + (size_t)lm * lda + kq * 8;
    const bf16* pb = B + (size_t)lm * ldb + kq * 8;
    for (int k = 0; k < K; k += 32) {
        bf16x8 av[4], bv[4];
#pragma unroll
        for (int t = 0; t < 4; ++t)
            av[t] = *(const bf16x8*)(pa + (size_t)(t * 16) * lda);
#pragma unroll
        for (int t = 0; t < 4; ++t)
            bv[t] = *(const bf16x8*)(pb + (size_t)(t * 16) * ldb);
#pragma unroll
        for (int i = 0; i < 4; ++i)
#pragma unroll
            for (int j = 0; j < 4; ++j)
                acc[i][j] = __builtin_amdgcn_mfma_f32_16x16x32_bf16(
                    av[i], bv[j], acc[i][j], 0, 0, 0);
        pa += 32;
        pb += 32;
    }
}

__device__ __forceinline__ void zero_acc(f32x4 (&acc)[4][4])
{
#pragma unroll
    for (int i = 0; i < 4; ++i)
#pragma unroll
        for (int j = 0; j < 4; ++j)
            acc[i][j] = (f32x4){0.f, 0.f, 0.f, 0.f};
}

// ------------------------------ prep kernels -------------------------------

__global__ __launch_bounds__(256) void prep_misc_kernel(
    const float* __restrict__ cv1_w,
    const float* __restrict__ qw, const float* __restrict__ qb,
    const float* __restrict__ kw, const float* __restrict__ kb,
    const float* __restrict__ vw, const float* __restrict__ vb,
    const float* __restrict__ ew, const float* __restrict__ eb,
    const float* __restrict__ cv2_w,
    const float* __restrict__ g1, const float* __restrict__ b1,
    const float* __restrict__ m1, const float* __restrict__ v1,
    const float* __restrict__ g2, const float* __restrict__ b2,
    const float* __restrict__ m2, const float* __restrict__ v2,
    bf16* __restrict__ w1b, bf16* __restrict__ wqkve, bf16* __restrict__ w2b,
    float* __restrict__ biasq,
    float* __restrict__ bn1s, float* __restrict__ bn1h,
    float* __restrict__ bn2s, float* __restrict__ bn2h)
{
    int idx = blockIdx.x * 256 + threadIdx.x;
    if (idx < 131072) { w1b[idx] = (bf16)cv1_w[idx]; return; }
    idx -= 131072;
    if (idx < 262144) {
        int j = idx >> 8, c = idx & 255;
        int p = j >> 8, r = j & 255;
        const float* w = (p == 0) ? qw : (p == 1) ? kw : (p == 2) ? vw : ew;
        wqkve[idx] = (bf16)w[r * 256 + c];
        return;
    }
    idx -= 262144;
    if (idx < 131072) { w2b[idx] = (bf16)cv2_w[idx]; return; }
    idx -= 131072;
    if (idx < 1024) {
        int p = idx >> 8, r = idx & 255;
        const float* bb = (p == 0) ? qb : (p == 1) ? kb : (p == 2) ? vb : eb;
        biasq[idx] = bb[r];
        return;
    }
    idx -= 1024;
    if (idx < 256) {
        float s = g1[idx] * rsqrtf(v1[idx] + 1e-5f);
        bn1s[idx] = s;
        bn1h[idx] = b1[idx] - m1[idx] * s;
        return;
    }
    idx -= 256;
    if (idx < 512) {
        float s = g2[idx] * rsqrtf(v2[idx] + 1e-5f);
        bn2s[idx] = s;
        bn2h[idx] = b2[idx] - m2[idx] * s;
        return;
    }
}

// pos_t[n][c] = rel_h[c][h] + rel_w[c][w],  n = h*64+w
__global__ __launch_bounds__(256) void pos_prep_kernel(
    const float* __restrict__ rel_h, const float* __restrict__ rel_w,
    bf16* __restrict__ pos_t)
{
    int n = blockIdx.x;
    int c = threadIdx.x;
    int h = n >> 6, w = n & 63;
    pos_t[(size_t)n * 256 + c] = (bf16)(rel_h[c * 64 + h] + rel_w[c * 64 + w]);
}

// xt[b*4096+n][d] = (bf16) x[b][d][n]
__global__ __launch_bounds__(256) void transpose_x_kernel(
    const float* __restrict__ x, bf16* __restrict__ xt)
{
    __shared__ float tile[64][65];
    int b = blockIdx.z;
    int n0 = blockIdx.x * 64;
    int d0 = blockIdx.y * 64;
    int tx = threadIdx.x & 63, ty = threadIdx.x >> 6;
#pragma unroll
    for (int i = 0; i < 16; ++i) {
        int d = i * 4 + ty;
        tile[d][tx] = x[((size_t)(b * 512 + d0 + d)) * 4096 + n0 + tx];
    }
    __syncthreads();
#pragma unroll
    for (int i = 0; i < 16; ++i) {
        int n = i * 4 + ty;
        xt[((size_t)(b * 4096 + n0 + n)) * 512 + d0 + tx] = (bf16)tile[tx][n];
    }
}

// v_cm[b][c][m] = qkvet[b*4096+m][512+c]
__global__ __launch_bounds__(256) void transpose_v_kernel(
    const bf16* __restrict__ qkvet, bf16* __restrict__ v_cm)
{
    __shared__ float tile[64][65];
    int b = blockIdx.z;
    int m0 = blockIdx.x * 64;
    int c0 = blockIdx.y * 64;
    int tx = threadIdx.x & 63, ty = threadIdx.x >> 6;
#pragma unroll
    for (int i = 0; i < 16; ++i) {
        int m = i * 4 + ty;
        tile[m][tx] = (float)qkvet[((size_t)(b * 4096 + m0 + m)) * 1024 + 512 + c0 + tx];
    }
    __syncthreads();
#pragma unroll
    for (int i = 0; i < 16; ++i) {
        int c = i * 4 + ty;
        v_cm[((size_t)(b * 256 + c0 + c)) * 4096 + m0 + tx] = (bf16)tile[tx][c];
    }
}

// ------------------------------ GEMM kernels -------------------------------

// x1t[row][col] = silu(bn1( sum_d xt[row][d] * w1b[col][d] ))
__global__ __launch_bounds__(256) void gemm1_kernel(
    const bf16* __restrict__ xt, const bf16* __restrict__ w1b,
    const float* __restrict__ bn1s, const float* __restrict__ bn1h,
    bf16* __restrict__ x1t)
{
    int wave = threadIdx.x >> 6;
    int m0 = blockIdx.y * 128 + (wave >> 1) * 64;
    int n0 = blockIdx.x * 128 + (wave & 1) * 64;
    f32x4 acc[4][4];
    zero_acc(acc);
    mfma_tile_accum(xt + (size_t)m0 * 512, 512, w1b + (size_t)n0 * 512, 512, 512, acc);
    int lane = threadIdx.x & 63;
    int lm = lane & 15, kq = lane >> 4;
#pragma unroll
    for (int i = 0; i < 4; ++i)
#pragma unroll
        for (int j = 0; j < 4; ++j)
#pragma unroll
            for (int r = 0; r < 4; ++r) {
                int row = m0 + i * 16 + kq * 4 + r;
                int col = n0 + j * 16 + lm;
                float h = bn1s[col] * acc[i][j][r] + bn1h[col];
                x1t[(size_t)row * 256 + col] = (bf16)silu_f(h);
            }
}

// qkvet[row][col] = sum_c x1t[row][c]*wqkve[col][c] + biasq[col]
__global__ __launch_bounds__(256) void gemm2_kernel(
    const bf16* __restrict__ x1t, const bf16* __restrict__ wqkve,
    const float* __restrict__ biasq, bf16* __restrict__ qkvet)
{
    int wave = threadIdx.x >> 6;
    int m0 = blockIdx.y * 128 + (wave >> 1) * 64;
    int n0 = blockIdx.x * 128 + (wave & 1) * 64;
    f32x4 acc[4][4];
    zero_acc(acc);
    mfma_tile_accum(x1t + (size_t)m0 * 256, 256, wqkve + (size_t)n0 * 256, 256, 256, acc);
    int lane = threadIdx.x & 63;
    int lm = lane & 15, kq = lane >> 4;
#pragma unroll
    for (int i = 0; i < 4; ++i)
#pragma unroll
        for (int j = 0; j < 4; ++j)
#pragma unroll
            for (int r = 0; r < 4; ++r) {
                int row = m0 + i * 16 + kq * 4 + r;
                int col = n0 + j * 16 + lm;
                qkvet[(size_t)row * 1024 + col] = (bf16)(acc[i][j][r] + biasq[col]);
            }
}

// S[n][m] = sum_c q[n][c]*k[m][c] + sum_c pos[n][c]*e[m][c]   (one batch)
__global__ __launch_bounds__(256) void gemm3_kernel(
    const bf16* __restrict__ qkvet, const bf16* __restrict__ pos_t,
    float* __restrict__ S, int b)
{
    const bf16* base = qkvet + (size_t)b * 4096 * 1024;
    int wave = threadIdx.x >> 6;
    int m0 = blockIdx.y * 128 + (wave >> 1) * 64;   // query n
    int n0 = blockIdx.x * 128 + (wave & 1) * 64;    // key m
    f32x4 acc[4][4];
    zero_acc(acc);
    // q . k
    mfma_tile_accum(base + (size_t)m0 * 1024 + 0, 1024,
                    base + (size_t)n0 * 1024 + 256, 1024, 256, acc);
    // pos . e
    mfma_tile_accum(pos_t + (size_t)m0 * 256, 256,
                    base + (size_t)n0 * 1024 + 768, 1024, 256, acc);
    int lane = threadIdx.x & 63;
    int lm = lane & 15, kq = lane >> 4;
#pragma unroll
    for (int i = 0; i < 4; ++i)
#pragma unroll
        for (int j = 0; j < 4; ++j)
#pragma unroll
            for (int r = 0; r < 4; ++r) {
                int row = m0 + i * 16 + kq * 4 + r;
                int col = n0 + j * 16 + lm;
                S[(size_t)row * 4096 + col] = acc[i][j][r];
            }
}

// P = softmax_rows(S), bf16 out. One block per row.
__global__ __launch_bounds__(256) void softmax_kernel(
    const float* __restrict__ S, bf16* __restrict__ P)
{
    __shared__ float red[4];
    int row = blockIdx.x;
    int t = threadIdx.x;
    int lane = t & 63, wid = t >> 6;
    const float* s = S + (size_t)row * 4096;
    float vals[16];
    float mx = -1e30f;
#pragma unroll
    for (int i = 0; i < 16; ++i) {
        vals[i] = s[t + 256 * i];
        mx = fmaxf(mx, vals[i]);
    }
#pragma unroll
    for (int o = 32; o > 0; o >>= 1) mx = fmaxf(mx, __shfl_down(mx, o));
    if (lane == 0) red[wid] = mx;
    __syncthreads();
    mx = fmaxf(fmaxf(red[0], red[1]), fmaxf(red[2], red[3]));
    __syncthreads();
    float sum = 0.f;
#pragma unroll
    for (int i = 0; i < 16; ++i) {
        vals[i] = __expf(vals[i] - mx);
        sum += vals[i];
    }
#pragma unroll
    for (int o = 32; o > 0; o >>= 1) sum += __shfl_down(sum, o);
    if (lane == 0) red[wid] = sum;
    __syncthreads();
    sum = red[0] + red[1] + red[2] + red[3];
    float inv = 1.f / sum;
    bf16* p = P + (size_t)row * 4096;
#pragma unroll
    for (int i = 0; i < 16; ++i)
        p[t + 256 * i] = (bf16)(vals[i] * inv);
}

// out_t[b*4096+n][c] = sum_m P[n][m] * v_cm[b][c][m]
__global__ __launch_bounds__(256) void gemm4_kernel(
    const bf16* __restrict__ P, const bf16* __restrict__ v_cm,
    bf16* __restrict__ out_t, int b)
{
    const bf16* vb = v_cm + (size_t)b * 256 * 4096;
    int wave = threadIdx.x >> 6;
    int m0 = blockIdx.y * 128 + (wave >> 1) * 64;   // n
    int n0 = blockIdx.x * 128 + (wave & 1) * 64;    // c
    f32x4 acc[4][4];
    zero_acc(acc);
    mfma_tile_accum(P + (size_t)m0 * 4096, 4096, vb + (size_t)n0 * 4096, 4096, 4096, acc);
    int lane = threadIdx.x & 63;
    int lm = lane & 15, kq = lane >> 4;
    bf16* ob = out_t + (size_t)b * 4096 * 256;
#pragma unroll
    for (int i = 0; i < 4; ++i)
#pragma unroll
        for (int j = 0; j < 4; ++j)
#pragma unroll
            for (int r = 0; r < 4; ++r) {
                int row = m0 + i * 16 + kq * 4 + r;
                int col = n0 + j * 16 + lm;
                ob[(size_t)row * 256 + col] = (bf16)acc[i][j][r];
            }
}

// d_out[b][d][n] = x[b][d][n] + silu(bn2( sum_c w2b[d][c]*out_t[b*4096+n][c] ))
__global__ __launch_bounds__(256) void gemm5_kernel(
    const bf16* __restrict__ w2b, const bf16* __restrict__ out_t,
    const float* __restrict__ bn2s, const float* __restrict__ bn2h,
    const float* __restrict__ x, float* __restrict__ out)
{
    int b = blockIdx.z;
    const bf16* B = out_t + (size_t)b * 4096 * 256;
    int wave = threadIdx.x >> 6;
    int m0 = blockIdx.y * 128 + (wave >> 1) * 64;   // d (512)
    int n0 = blockIdx.x * 128 + (wave & 1) * 64;    // n (4096)
    f32x4 acc[4][4];
    zero_acc(acc);
    mfma_tile_accum(w2b + (size_t)m0 * 256, 256, B + (size_t)n0 * 256, 256, 256, acc);
    int lane = threadIdx.x & 63;
    int lm = lane & 15, kq = lane >> 4;
#pragma unroll
    for (int i = 0; i < 4; ++i)
#pragma unroll
        for (int j = 0; j < 4; ++j)
#pragma unroll
            for (int r = 0; r < 4; ++r) {
                int d = m0 + i * 16 + kq * 4 + r;
                int n = n0 + j * 16 + lm;
                float h = bn2s[d] * acc[i][j][r] + bn2h[d];
                size_t gi = ((size_t)(b * 512 + d)) * 4096 + n;
                out[gi] = x[gi] + silu_f(h);
            }
}

// ------------------------------- launcher ----------------------------------

extern "C" void kernel_launch(void* const* d_in, const int* in_sizes, int n_in,
                              void* d_out, int out_size, void* d_ws, size_t ws_size,
                              hipStream_t stream)
{
    (void)in_sizes; (void)n_in; (void)out_size; (void)ws_size;
    const float* x     = (const float*)d_in[0];
    const float* cv1_w = (const float*)d_in[1];
    const float* bn1_g = (const float*)d_in[2];
    const float* bn1_b = (const float*)d_in[3];
    const float* bn1_m = (const float*)d_in[4];
    const float* bn1_v = (const float*)d_in[5];
    const float* q_w   = (const float*)d_in[6];
    const float* q_b   = (const float*)d_in[7];
    const float* k_w   = (const float*)d_in[8];
    const float* k_b   = (const float*)d_in[9];
    const float* v_w   = (const float*)d_in[10];
    const float* v_b   = (const float*)d_in[11];
    const float* e_w   = (const float*)d_in[12];
    const float* e_b   = (const float*)d_in[13];
    const float* rel_h = (const float*)d_in[14];
    const float* rel_w = (const float*)d_in[15];
    const float* cv2_w = (const float*)d_in[16];
    const float* bn2_g = (const float*)d_in[17];
    const float* bn2_b = (const float*)d_in[18];
    const float* bn2_m = (const float*)d_in[19];
    const float* bn2_v = (const float*)d_in[20];
    float* out = (float*)d_out;

    char* ws = (char*)d_ws;
    // ws layout (bytes). out_t overlays xt (xt dead after gemm1).
    bf16* xt    = (bf16*)(ws + 0);            // 32 MB  [32768][512]
    bf16* out_t = (bf16*)(ws + 0);            // 16 MB  [32768][256] (overlay)
    bf16* x1t   = (bf16*)(ws + 33554432);     // 16 MB  [32768][256]
    bf16* qkvet = (bf16*)(ws + 50331648);     // 64 MB  [32768][1024]
    bf16* v_cm  = (bf16*)(ws + 117440512);    // 16 MB  [8][256][4096]
    bf16* pos_t = (bf16*)(ws + 134217728);    //  2 MB  [4096][256]
    float* S    = (float*)(ws + 136314880);   // 64 MB  [4096][4096] (per-batch reuse)
    bf16* P     = (bf16*)(ws + 203423744);    // 32 MB  [4096][4096] (per-batch reuse)
    bf16* w1b   = (bf16*)(ws + 236978176);    // 256 KB
    bf16* wqkve = (bf16*)(ws + 237240320);    // 512 KB
    bf16* w2b   = (bf16*)(ws + 237764608);    // 256 KB
    float* biasq= (float*)(ws + 238026752);   // 4 KB
    float* bn1s = (float*)(ws + 238030848);
    float* bn1h = (float*)(ws + 238031872);
    float* bn2s = (float*)(ws + 238032896);
    float* bn2h = (float*)(ws + 238034944);

    prep_misc_kernel<<<2055, 256, 0, stream>>>(
        cv1_w, q_w, q_b, k_w, k_b, v_w, v_b, e_w, e_b, cv2_w,
        bn1_g, bn1_b, bn1_m, bn1_v, bn2_g, bn2_b, bn2_m, bn2_v,
        w1b, wqkve, w2b, biasq, bn1s, bn1h, bn2s, bn2h);
    pos_prep_kernel<<<4096, 256, 0, stream>>>(rel_h, rel_w, pos_t);
    transpose_x_kernel<<<dim3(64, 8, 8), 256, 0, stream>>>(x, xt);
    gemm1_kernel<<<dim3(2, 256), 256, 0, stream>>>(xt, w1b, bn1s, bn1h, x1t);
    gemm2_kernel<<<dim3(8, 256), 256, 0, stream>>>(x1t, wqkve, biasq, qkvet);
    transpose_v_kernel<<<dim3(64, 4, 8), 256, 0, stream>>>(qkvet, v_cm);
    for (int b = 0; b < 8; ++b) {
        gemm3_kernel<<<dim3(32, 32), 256, 0, stream>>>(qkvet, pos_t, S, b);
        softmax_kernel<<<4096, 256, 0, stream>>>(S, P);
        gemm4_kernel<<<dim3(2, 32), 256, 0, stream>>>(P, v_cm, out_t, b);
    }
    gemm5_kernel<<<dim3(32, 4, 8), 256, 0, stream>>>(w2b, out_t, bn2s, bn2h, x, out);
}

// Round 2
// 786.246 us; speedup vs baseline: 2.5644x; 2.5644x over previous
//
#include <hip/hip_runtime.h>

// ---------------------------------------------------------------------------
// ExtraPositionPromptSABottleneck on MI355X (gfx950)
// B=8, DIMS=512, C=256, H=W=64, N=4096.
//
// Round 2 restructure:
//  - gemm2 scatters projections into qp=[q|pos] (pos filled separately),
//    ke=[k|e], v_nm.  Attention logits become ONE GEMM: S = qp . ke^T, K=512.
//  - Attention runs in 2 groups of 4 batches; logits stored bf16 in P_grp
//    (128 MB), softmax in-place (bf16x8 vectorized), then batched PV GEMM.
//  - gemm3/gemm4 use an m97-style LDS-staged core: 128x128 block tile, BK=32,
//    global_load_lds width-16 staging, 4 waves x (64x64) MFMA tiles.
// ---------------------------------------------------------------------------

typedef __bf16 bf16;
typedef __attribute__((ext_vector_type(8))) __bf16 bf16x8;
typedef __attribute__((ext_vector_type(4))) float f32x4;

__device__ __forceinline__ float silu_f(float x) { return x / (1.f + __expf(-x)); }

__device__ __forceinline__ void zero_acc(f32x4 (&acc)[4][4])
{
#pragma unroll
    for (int i = 0; i < 4; ++i)
#pragma unroll
        for (int j = 0; j < 4; ++j)
            acc[i][j] = (f32x4){0.f, 0.f, 0.f, 0.f};
}

// Direct-global 64x64 wave tile accumulate (used by small GEMMs 1/2/5).
__device__ __forceinline__ void mfma_tile_accum(
    const bf16* __restrict__ A, int lda,
    const bf16* __restrict__ B, int ldb,
    int K, f32x4 (&acc)[4][4])
{
    const int lane = threadIdx.x & 63;
    const int lm = lane & 15;
    const int kq = lane >> 4;
    const bf16* pa = A + (size_t)lm * lda + kq * 8;
    const bf16* pb = B + (size_t)lm * ldb + kq * 8;
    for (int k = 0; k < K; k += 32) {
        bf16x8 av[4], bv[4];
#pragma unroll
        for (int t = 0; t < 4; ++t)
            av[t] = *(const bf16x8*)(pa + (size_t)(t * 16) * lda);
#pragma unroll
        for (int t = 0; t < 4; ++t)
            bv[t] = *(const bf16x8*)(pb + (size_t)(t * 16) * ldb);
#pragma unroll
        for (int i = 0; i < 4; ++i)
#pragma unroll
            for (int j = 0; j < 4; ++j)
                acc[i][j] = __builtin_amdgcn_mfma_f32_16x16x32_bf16(
                    av[i], bv[j], acc[i][j], 0, 0, 0);
        pa += 32;
        pb += 32;
    }
}

// ---- LDS-staged GEMM core (m97 structure): block 256 thr, tile 128x128, BK=32
__device__ __forceinline__ void load_lds16(const bf16* g, bf16* l)
{
    __builtin_amdgcn_global_load_lds(
        (const __attribute__((address_space(1))) unsigned int*)g,
        (__attribute__((address_space(3))) unsigned int*)l, 16, 0, 0);
}

// A: block's 128 rows, k-contig stride lda. B: block's 128 "cols", stride ldb.
__device__ __forceinline__ void gemm_core_lds(
    const bf16* __restrict__ A, int lda,
    const bf16* __restrict__ B, int ldb,
    int K, f32x4 (&acc)[4][4])
{
    __shared__ bf16 As[128 * 32];
    __shared__ bf16 Bs[128 * 32];
    const int tid = threadIdx.x;
    const int wave = tid >> 6;
    const int lane = tid & 63;
    const int lm = lane & 15;
    const int kq = lane >> 4;
    const int m0 = (wave >> 1) * 64;
    const int n0 = (wave & 1) * 64;
    // staging: each thread supplies 16B per round; 2 rounds per matrix.
    const int srow = tid >> 2;          // rows 0..63 (round 0), +64 (round 1)
    const int skoff = (tid & 3) * 8;    // k element offset within BK=32
    bf16* lA = As + tid * 8;            // LDS dest = wave_base + lane*16B
    bf16* lB = Bs + tid * 8;
    zero_acc(acc);
    for (int k0 = 0; k0 < K; k0 += 32) {
        const bf16* ga = A + (size_t)srow * lda + k0 + skoff;
        const bf16* gb = B + (size_t)srow * ldb + k0 + skoff;
        load_lds16(ga, lA);
        load_lds16(ga + (size_t)64 * lda, lA + 64 * 32);
        load_lds16(gb, lB);
        load_lds16(gb + (size_t)64 * ldb, lB + 64 * 32);
        __syncthreads();
        bf16x8 av[4], bv[4];
#pragma unroll
        for (int t = 0; t < 4; ++t)
            av[t] = *(const bf16x8*)(As + (m0 + t * 16 + lm) * 32 + kq * 8);
#pragma unroll
        for (int t = 0; t < 4; ++t)
            bv[t] = *(const bf16x8*)(Bs + (n0 + t * 16 + lm) * 32 + kq * 8);
#pragma unroll
        for (int i = 0; i < 4; ++i)
#pragma unroll
            for (int j = 0; j < 4; ++j)
                acc[i][j] = __builtin_amdgcn_mfma_f32_16x16x32_bf16(
                    av[i], bv[j], acc[i][j], 0, 0, 0);
        __syncthreads();
    }
}

// ------------------------------ prep kernels -------------------------------

__global__ __launch_bounds__(256) void prep_misc_kernel(
    const float* __restrict__ cv1_w,
    const float* __restrict__ qw, const float* __restrict__ qb,
    const float* __restrict__ kw, const float* __restrict__ kb,
    const float* __restrict__ vw, const float* __restrict__ vb,
    const float* __restrict__ ew, const float* __restrict__ eb,
    const float* __restrict__ cv2_w,
    const float* __restrict__ g1, const float* __restrict__ b1,
    const float* __restrict__ m1, const float* __restrict__ v1,
    const float* __restrict__ g2, const float* __restrict__ b2,
    const float* __restrict__ m2, const float* __restrict__ v2,
    bf16* __restrict__ w1b, bf16* __restrict__ wqkve, bf16* __restrict__ w2b,
    float* __restrict__ biasq,
    float* __restrict__ bn1s, float* __restrict__ bn1h,
    float* __restrict__ bn2s, float* __restrict__ bn2h)
{
    int idx = blockIdx.x * 256 + threadIdx.x;
    if (idx < 131072) { w1b[idx] = (bf16)cv1_w[idx]; return; }
    idx -= 131072;
    if (idx < 262144) {
        int j = idx >> 8, c = idx & 255;
        int p = j >> 8, r = j & 255;
        const float* w = (p == 0) ? qw : (p == 1) ? kw : (p == 2) ? vw : ew;
        wqkve[idx] = (bf16)w[r * 256 + c];
        return;
    }
    idx -= 262144;
    if (idx < 131072) { w2b[idx] = (bf16)cv2_w[idx]; return; }
    idx -= 131072;
    if (idx < 1024) {
        int p = idx >> 8, r = idx & 255;
        const float* bb = (p == 0) ? qb : (p == 1) ? kb : (p == 2) ? vb : eb;
        biasq[idx] = bb[r];
        return;
    }
    idx -= 1024;
    if (idx < 256) {
        float s = g1[idx] * rsqrtf(v1[idx] + 1e-5f);
        bn1s[idx] = s;
        bn1h[idx] = b1[idx] - m1[idx] * s;
        return;
    }
    idx -= 256;
    if (idx < 512) {
        float s = g2[idx] * rsqrtf(v2[idx] + 1e-5f);
        bn2s[idx] = s;
        bn2h[idx] = b2[idx] - m2[idx] * s;
        return;
    }
}

// qp[b*4096+n][256+c] = rel_h[c][h] + rel_w[c][w] for all b (pos half of qp)
__global__ __launch_bounds__(256) void pos_prep_kernel(
    const float* __restrict__ rel_h, const float* __restrict__ rel_w,
    bf16* __restrict__ qp)
{
    int n = blockIdx.x;
    int c = threadIdx.x;
    int h = n >> 6, w = n & 63;
    bf16 val = (bf16)(rel_h[c * 64 + h] + rel_w[c * 64 + w]);
#pragma unroll
    for (int b = 0; b < 8; ++b)
        qp[((size_t)(b * 4096 + n)) * 512 + 256 + c] = val;
}

// xt[b*4096+n][d] = (bf16) x[b][d][n]
__global__ __launch_bounds__(256) void transpose_x_kernel(
    const float* __restrict__ x, bf16* __restrict__ xt)
{
    __shared__ float tile[64][65];
    int b = blockIdx.z;
    int n0 = blockIdx.x * 64;
    int d0 = blockIdx.y * 64;
    int tx = threadIdx.x & 63, ty = threadIdx.x >> 6;
#pragma unroll
    for (int i = 0; i < 16; ++i) {
        int d = i * 4 + ty;
        tile[d][tx] = x[((size_t)(b * 512 + d0 + d)) * 4096 + n0 + tx];
    }
    __syncthreads();
#pragma unroll
    for (int i = 0; i < 16; ++i) {
        int n = i * 4 + ty;
        xt[((size_t)(b * 4096 + n0 + n)) * 512 + d0 + tx] = (bf16)tile[tx][n];
    }
}

// v_cm[b][c][m] = v_nm[b*4096+m][c]
__global__ __launch_bounds__(256) void transpose_v_kernel(
    const bf16* __restrict__ v_nm, bf16* __restrict__ v_cm)
{
    __shared__ float tile[64][65];
    int b = blockIdx.z;
    int m0 = blockIdx.x * 64;
    int c0 = blockIdx.y * 64;
    int tx = threadIdx.x & 63, ty = threadIdx.x >> 6;
#pragma unroll
    for (int i = 0; i < 16; ++i) {
        int m = i * 4 + ty;
        tile[m][tx] = (float)v_nm[((size_t)(b * 4096 + m0 + m)) * 256 + c0 + tx];
    }
    __syncthreads();
#pragma unroll
    for (int i = 0; i < 16; ++i) {
        int c = i * 4 + ty;
        v_cm[((size_t)(b * 256 + c0 + c)) * 4096 + m0 + tx] = (bf16)tile[tx][c];
    }
}

// ------------------------------ GEMM kernels -------------------------------

// x1t[row][col] = silu(bn1( sum_d xt[row][d] * w1b[col][d] ))
__global__ __launch_bounds__(256) void gemm1_kernel(
    const bf16* __restrict__ xt, const bf16* __restrict__ w1b,
    const float* __restrict__ bn1s, const float* __restrict__ bn1h,
    bf16* __restrict__ x1t)
{
    int wave = threadIdx.x >> 6;
    int m0 = blockIdx.y * 128 + (wave >> 1) * 64;
    int n0 = blockIdx.x * 128 + (wave & 1) * 64;
    f32x4 acc[4][4];
    zero_acc(acc);
    mfma_tile_accum(xt + (size_t)m0 * 512, 512, w1b + (size_t)n0 * 512, 512, 512, acc);
    int lane = threadIdx.x & 63;
    int lm = lane & 15, kq = lane >> 4;
#pragma unroll
    for (int i = 0; i < 4; ++i)
#pragma unroll
        for (int j = 0; j < 4; ++j)
#pragma unroll
            for (int r = 0; r < 4; ++r) {
                int row = m0 + i * 16 + kq * 4 + r;
                int col = n0 + j * 16 + lm;
                float h = bn1s[col] * acc[i][j][r] + bn1h[col];
                x1t[(size_t)row * 256 + col] = (bf16)silu_f(h);
            }
}

// projections: col<256 -> qp[.][col]; <512 -> ke[.][col-256];
//              <768 -> v_nm[.][col-512]; else ke[.][256+col-768]
__global__ __launch_bounds__(256) void gemm2_kernel(
    const bf16* __restrict__ x1t, const bf16* __restrict__ wqkve,
    const float* __restrict__ biasq,
    bf16* __restrict__ qp, bf16* __restrict__ ke, bf16* __restrict__ v_nm)
{
    int wave = threadIdx.x >> 6;
    int m0 = blockIdx.y * 128 + (wave >> 1) * 64;
    int n0 = blockIdx.x * 128 + (wave & 1) * 64;
    f32x4 acc[4][4];
    zero_acc(acc);
    mfma_tile_accum(x1t + (size_t)m0 * 256, 256, wqkve + (size_t)n0 * 256, 256, 256, acc);
    int lane = threadIdx.x & 63;
    int lm = lane & 15, kq = lane >> 4;
#pragma unroll
    for (int i = 0; i < 4; ++i)
#pragma unroll
        for (int j = 0; j < 4; ++j)
#pragma unroll
            for (int r = 0; r < 4; ++r) {
                int row = m0 + i * 16 + kq * 4 + r;
                int col = n0 + j * 16 + lm;
                bf16 val = (bf16)(acc[i][j][r] + biasq[col]);
                if (col < 256)       qp[(size_t)row * 512 + col] = val;
                else if (col < 512)  ke[(size_t)row * 512 + (col - 256)] = val;
                else if (col < 768)  v_nm[(size_t)row * 256 + (col - 512)] = val;
                else                 ke[(size_t)row * 512 + 256 + (col - 768)] = val;
            }
}

// P[bz][n][m] = qp[b,n,:] . ke[b,m,:]  (K=512), bf16 out, batched group of 4
__global__ __launch_bounds__(256) void gemm3b_kernel(
    const bf16* __restrict__ qp, const bf16* __restrict__ ke,
    bf16* __restrict__ P, int gbase)
{
    int bz = blockIdx.z;
    int b = gbase + bz;
    const bf16* A = qp + ((size_t)b * 4096 + blockIdx.y * 128) * 512;
    const bf16* Bm = ke + ((size_t)b * 4096 + blockIdx.x * 128) * 512;
    f32x4 acc[4][4];
    gemm_core_lds(A, 512, Bm, 512, 512, acc);
    int wave = threadIdx.x >> 6;
    int lane = threadIdx.x & 63;
    int m0 = (wave >> 1) * 64, n0 = (wave & 1) * 64;
    int lm = lane & 15, kq = lane >> 4;
    bf16* Pb = P + ((size_t)bz * 4096 + blockIdx.y * 128) * 4096 + blockIdx.x * 128;
#pragma unroll
    for (int i = 0; i < 4; ++i)
#pragma unroll
        for (int j = 0; j < 4; ++j)
#pragma unroll
            for (int r = 0; r < 4; ++r)
                Pb[(size_t)(m0 + i * 16 + kq * 4 + r) * 4096 + n0 + j * 16 + lm] =
                    (bf16)acc[i][j][r];
}

// in-place row softmax on bf16 P (16384 rows x 4096)
__global__ __launch_bounds__(256) void softmax_b_kernel(bf16* __restrict__ P)
{
    __shared__ float red[4];
    bf16* p = P + (size_t)blockIdx.x * 4096;
    int t = threadIdx.x;
    int lane = t & 63, wid = t >> 6;
    float v[16];
    bf16x8 h0 = *(const bf16x8*)(p + t * 16);
    bf16x8 h1 = *(const bf16x8*)(p + t * 16 + 8);
#pragma unroll
    for (int i = 0; i < 8; ++i) { v[i] = (float)h0[i]; v[8 + i] = (float)h1[i]; }
    float mx = -1e30f;
#pragma unroll
    for (int i = 0; i < 16; ++i) mx = fmaxf(mx, v[i]);
#pragma unroll
    for (int o = 32; o > 0; o >>= 1) mx = fmaxf(mx, __shfl_down(mx, o));
    if (lane == 0) red[wid] = mx;
    __syncthreads();
    mx = fmaxf(fmaxf(red[0], red[1]), fmaxf(red[2], red[3]));
    __syncthreads();
    float sum = 0.f;
#pragma unroll
    for (int i = 0; i < 16; ++i) {
        v[i] = __expf(v[i] - mx);
        sum += v[i];
    }
#pragma unroll
    for (int o = 32; o > 0; o >>= 1) sum += __shfl_down(sum, o);
    if (lane == 0) red[wid] = sum;
    __syncthreads();
    float inv = 1.f / (red[0] + red[1] + red[2] + red[3]);
    bf16x8 o0, o1;
#pragma unroll
    for (int i = 0; i < 8; ++i) {
        o0[i] = (bf16)(v[i] * inv);
        o1[i] = (bf16)(v[8 + i] * inv);
    }
    *(bf16x8*)(p + t * 16) = o0;
    *(bf16x8*)(p + t * 16 + 8) = o1;
}

// out_t[(gbase+bz)*4096+n][c] = sum_m P[bz][n][m] * v_cm[gbase+bz][c][m]
__global__ __launch_bounds__(256) void gemm4b_kernel(
    const bf16* __restrict__ P, const bf16* __restrict__ v_cm,
    bf16* __restrict__ out_t, int gbase)
{
    int bz = blockIdx.z;
    int b = gbase + bz;
    const bf16* A = P + ((size_t)bz * 4096 + blockIdx.y * 128) * 4096;
    const bf16* Bm = v_cm + ((size_t)b * 256 + blockIdx.x * 128) * 4096;
    f32x4 acc[4][4];
    gemm_core_lds(A, 4096, Bm, 4096, 4096, acc);
    int wave = threadIdx.x >> 6;
    int lane = threadIdx.x & 63;
    int m0 = (wave >> 1) * 64, n0 = (wave & 1) * 64;
    int lm = lane & 15, kq = lane >> 4;
    bf16* ob = out_t + ((size_t)b * 4096 + blockIdx.y * 128) * 256 + blockIdx.x * 128;
#pragma unroll
    for (int i = 0; i < 4; ++i)
#pragma unroll
        for (int j = 0; j < 4; ++j)
#pragma unroll
            for (int r = 0; r < 4; ++r)
                ob[(size_t)(m0 + i * 16 + kq * 4 + r) * 256 + n0 + j * 16 + lm] =
                    (bf16)acc[i][j][r];
}

// d_out[b][d][n] = x[b][d][n] + silu(bn2( sum_c w2b[d][c]*out_t[b*4096+n][c] ))
__global__ __launch_bounds__(256) void gemm5_kernel(
    const bf16* __restrict__ w2b, const bf16* __restrict__ out_t,
    const float* __restrict__ bn2s, const float* __restrict__ bn2h,
    const float* __restrict__ x, float* __restrict__ out)
{
    int b = blockIdx.z;
    const bf16* B = out_t + (size_t)b * 4096 * 256;
    int wave = threadIdx.x >> 6;
    int m0 = blockIdx.y * 128 + (wave >> 1) * 64;   // d (512)
    int n0 = blockIdx.x * 128 + (wave & 1) * 64;    // n (4096)
    f32x4 acc[4][4];
    zero_acc(acc);
    mfma_tile_accum(w2b + (size_t)m0 * 256, 256, B + (size_t)n0 * 256, 256, 256, acc);
    int lane = threadIdx.x & 63;
    int lm = lane & 15, kq = lane >> 4;
#pragma unroll
    for (int i = 0; i < 4; ++i)
#pragma unroll
        for (int j = 0; j < 4; ++j)
#pragma unroll
            for (int r = 0; r < 4; ++r) {
                int d = m0 + i * 16 + kq * 4 + r;
                int n = n0 + j * 16 + lm;
                float h = bn2s[d] * acc[i][j][r] + bn2h[d];
                size_t gi = ((size_t)(b * 512 + d)) * 4096 + n;
                out[gi] = x[gi] + silu_f(h);
            }
}

// ------------------------------- launcher ----------------------------------

extern "C" void kernel_launch(void* const* d_in, const int* in_sizes, int n_in,
                              void* d_out, int out_size, void* d_ws, size_t ws_size,
                              hipStream_t stream)
{
    (void)in_sizes; (void)n_in; (void)out_size; (void)ws_size;
    const float* x     = (const float*)d_in[0];
    const float* cv1_w = (const float*)d_in[1];
    const float* bn1_g = (const float*)d_in[2];
    const float* bn1_b = (const float*)d_in[3];
    const float* bn1_m = (const float*)d_in[4];
    const float* bn1_v = (const float*)d_in[5];
    const float* q_w   = (const float*)d_in[6];
    const float* q_b   = (const float*)d_in[7];
    const float* k_w   = (const float*)d_in[8];
    const float* k_b   = (const float*)d_in[9];
    const float* v_w   = (const float*)d_in[10];
    const float* v_b   = (const float*)d_in[11];
    const float* e_w   = (const float*)d_in[12];
    const float* e_b   = (const float*)d_in[13];
    const float* rel_h = (const float*)d_in[14];
    const float* rel_w = (const float*)d_in[15];
    const float* cv2_w = (const float*)d_in[16];
    const float* bn2_g = (const float*)d_in[17];
    const float* bn2_b = (const float*)d_in[18];
    const float* bn2_m = (const float*)d_in[19];
    const float* bn2_v = (const float*)d_in[20];
    float* out = (float*)d_out;

    char* ws = (char*)d_ws;
    // P_grp region (128 MB) also hosts xt/x1t/v_nm (all dead before attention)
    bf16* P     = (bf16*)(ws + 0);            // 128 MB [4][4096][4096]
    bf16* xt    = (bf16*)(ws + 0);            //  32 MB overlay
    bf16* x1t   = (bf16*)(ws + 33554432);     //  16 MB overlay
    bf16* v_nm  = (bf16*)(ws + 50331648);     //  16 MB overlay
    bf16* qp    = (bf16*)(ws + 134217728);    //  32 MB [32768][512]
    bf16* ke    = (bf16*)(ws + 167772160);    //  32 MB [32768][512]
    bf16* v_cm  = (bf16*)(ws + 201326592);    //  16 MB [8][256][4096]
    bf16* out_t = (bf16*)(ws + 218103808);    //  16 MB [32768][256]
    bf16* w1b   = (bf16*)(ws + 234881024);    // 256 KB
    bf16* wqkve = (bf16*)(ws + 235143168);    // 512 KB
    bf16* w2b   = (bf16*)(ws + 235667456);    // 256 KB
    float* biasq= (float*)(ws + 235929600);   //   4 KB
    float* bn1s = (float*)(ws + 235933696);
    float* bn1h = (float*)(ws + 235934720);
    float* bn2s = (float*)(ws + 235935744);
    float* bn2h = (float*)(ws + 235937792);

    prep_misc_kernel<<<2055, 256, 0, stream>>>(
        cv1_w, q_w, q_b, k_w, k_b, v_w, v_b, e_w, e_b, cv2_w,
        bn1_g, bn1_b, bn1_m, bn1_v, bn2_g, bn2_b, bn2_m, bn2_v,
        w1b, wqkve, w2b, biasq, bn1s, bn1h, bn2s, bn2h);
    transpose_x_kernel<<<dim3(64, 8, 8), 256, 0, stream>>>(x, xt);
    gemm1_kernel<<<dim3(2, 256), 256, 0, stream>>>(xt, w1b, bn1s, bn1h, x1t);
    gemm2_kernel<<<dim3(8, 256), 256, 0, stream>>>(x1t, wqkve, biasq, qp, ke, v_nm);
    pos_prep_kernel<<<4096, 256, 0, stream>>>(rel_h, rel_w, qp);
    transpose_v_kernel<<<dim3(64, 4, 8), 256, 0, stream>>>(v_nm, v_cm);
    for (int g = 0; g < 2; ++g) {
        gemm3b_kernel<<<dim3(32, 32, 4), 256, 0, stream>>>(qp, ke, P, g * 4);
        softmax_b_kernel<<<16384, 256, 0, stream>>>(P);
        gemm4b_kernel<<<dim3(2, 32, 4), 256, 0, stream>>>(P, v_cm, out_t, g * 4);
    }
    gemm5_kernel<<<dim3(32, 4, 8), 256, 0, stream>>>(w2b, out_t, bn2s, bn2h, x, out);
}

// Round 3
// 733.975 us; speedup vs baseline: 2.7471x; 1.0712x over previous
//
#include <hip/hip_runtime.h>

// ---------------------------------------------------------------------------
// ExtraPositionPromptSABottleneck on MI355X (gfx950)
// B=8, DIMS=512, C=256, H=W=64, N=4096.
//
// Round 3: all five GEMMs now use the m97-style LDS-staged core
// (128x128 block tile, BK=32, global_load_lds width-16, 4 waves x 64x64).
// Round 2 had gemm1/2/5 on direct-global loads -> latency-bound
// (gemm5: 110 us, MfmaUtil 2.9%).
// ---------------------------------------------------------------------------

typedef __bf16 bf16;
typedef __attribute__((ext_vector_type(8))) __bf16 bf16x8;
typedef __attribute__((ext_vector_type(4))) float f32x4;

__device__ __forceinline__ float silu_f(float x) { return x / (1.f + __expf(-x)); }

__device__ __forceinline__ void zero_acc(f32x4 (&acc)[4][4])
{
#pragma unroll
    for (int i = 0; i < 4; ++i)
#pragma unroll
        for (int j = 0; j < 4; ++j)
            acc[i][j] = (f32x4){0.f, 0.f, 0.f, 0.f};
}

// ---- LDS-staged GEMM core: block 256 thr, tile 128x128, BK=32
__device__ __forceinline__ void load_lds16(const bf16* g, bf16* l)
{
    __builtin_amdgcn_global_load_lds(
        (const __attribute__((address_space(1))) unsigned int*)g,
        (__attribute__((address_space(3))) unsigned int*)l, 16, 0, 0);
}

// A: block's 128 rows, k-contig stride lda. B: block's 128 "cols", stride ldb.
__device__ __forceinline__ void gemm_core_lds(
    const bf16* __restrict__ A, int lda,
    const bf16* __restrict__ B, int ldb,
    int K, f32x4 (&acc)[4][4])
{
    __shared__ bf16 As[128 * 32];
    __shared__ bf16 Bs[128 * 32];
    const int tid = threadIdx.x;
    const int wave = tid >> 6;
    const int lane = tid & 63;
    const int lm = lane & 15;
    const int kq = lane >> 4;
    const int m0 = (wave >> 1) * 64;
    const int n0 = (wave & 1) * 64;
    // staging: each thread supplies 16B per round; 2 rounds per matrix.
    const int srow = tid >> 2;          // rows 0..63 (round 0), +64 (round 1)
    const int skoff = (tid & 3) * 8;    // k element offset within BK=32
    bf16* lA = As + tid * 8;            // LDS dest = wave_base + lane*16B
    bf16* lB = Bs + tid * 8;
    zero_acc(acc);
    for (int k0 = 0; k0 < K; k0 += 32) {
        const bf16* ga = A + (size_t)srow * lda + k0 + skoff;
        const bf16* gb = B + (size_t)srow * ldb + k0 + skoff;
        load_lds16(ga, lA);
        load_lds16(ga + (size_t)64 * lda, lA + 64 * 32);
        load_lds16(gb, lB);
        load_lds16(gb + (size_t)64 * ldb, lB + 64 * 32);
        __syncthreads();
        bf16x8 av[4], bv[4];
#pragma unroll
        for (int t = 0; t < 4; ++t)
            av[t] = *(const bf16x8*)(As + (m0 + t * 16 + lm) * 32 + kq * 8);
#pragma unroll
        for (int t = 0; t < 4; ++t)
            bv[t] = *(const bf16x8*)(Bs + (n0 + t * 16 + lm) * 32 + kq * 8);
#pragma unroll
        for (int i = 0; i < 4; ++i)
#pragma unroll
            for (int j = 0; j < 4; ++j)
                acc[i][j] = __builtin_amdgcn_mfma_f32_16x16x32_bf16(
                    av[i], bv[j], acc[i][j], 0, 0, 0);
        __syncthreads();
    }
}

// ------------------------------ prep kernels -------------------------------

__global__ __launch_bounds__(256) void prep_misc_kernel(
    const float* __restrict__ cv1_w,
    const float* __restrict__ qw, const float* __restrict__ qb,
    const float* __restrict__ kw, const float* __restrict__ kb,
    const float* __restrict__ vw, const float* __restrict__ vb,
    const float* __restrict__ ew, const float* __restrict__ eb,
    const float* __restrict__ cv2_w,
    const float* __restrict__ g1, const float* __restrict__ b1,
    const float* __restrict__ m1, const float* __restrict__ v1,
    const float* __restrict__ g2, const float* __restrict__ b2,
    const float* __restrict__ m2, const float* __restrict__ v2,
    bf16* __restrict__ w1b, bf16* __restrict__ wqkve, bf16* __restrict__ w2b,
    float* __restrict__ biasq,
    float* __restrict__ bn1s, float* __restrict__ bn1h,
    float* __restrict__ bn2s, float* __restrict__ bn2h)
{
    int idx = blockIdx.x * 256 + threadIdx.x;
    if (idx < 131072) { w1b[idx] = (bf16)cv1_w[idx]; return; }
    idx -= 131072;
    if (idx < 262144) {
        int j = idx >> 8, c = idx & 255;
        int p = j >> 8, r = j & 255;
        const float* w = (p == 0) ? qw : (p == 1) ? kw : (p == 2) ? vw : ew;
        wqkve[idx] = (bf16)w[r * 256 + c];
        return;
    }
    idx -= 262144;
    if (idx < 131072) { w2b[idx] = (bf16)cv2_w[idx]; return; }
    idx -= 131072;
    if (idx < 1024) {
        int p = idx >> 8, r = idx & 255;
        const float* bb = (p == 0) ? qb : (p == 1) ? kb : (p == 2) ? vb : eb;
        biasq[idx] = bb[r];
        return;
    }
    idx -= 1024;
    if (idx < 256) {
        float s = g1[idx] * rsqrtf(v1[idx] + 1e-5f);
        bn1s[idx] = s;
        bn1h[idx] = b1[idx] - m1[idx] * s;
        return;
    }
    idx -= 256;
    if (idx < 512) {
        float s = g2[idx] * rsqrtf(v2[idx] + 1e-5f);
        bn2s[idx] = s;
        bn2h[idx] = b2[idx] - m2[idx] * s;
        return;
    }
}

// qp[b*4096+n][256+c] = rel_h[c][h] + rel_w[c][w] for all b (pos half of qp)
__global__ __launch_bounds__(256) void pos_prep_kernel(
    const float* __restrict__ rel_h, const float* __restrict__ rel_w,
    bf16* __restrict__ qp)
{
    int n = blockIdx.x;
    int c = threadIdx.x;
    int h = n >> 6, w = n & 63;
    bf16 val = (bf16)(rel_h[c * 64 + h] + rel_w[c * 64 + w]);
#pragma unroll
    for (int b = 0; b < 8; ++b)
        qp[((size_t)(b * 4096 + n)) * 512 + 256 + c] = val;
}

// xt[b*4096+n][d] = (bf16) x[b][d][n]
__global__ __launch_bounds__(256) void transpose_x_kernel(
    const float* __restrict__ x, bf16* __restrict__ xt)
{
    __shared__ float tile[64][65];
    int b = blockIdx.z;
    int n0 = blockIdx.x * 64;
    int d0 = blockIdx.y * 64;
    int tx = threadIdx.x & 63, ty = threadIdx.x >> 6;
#pragma unroll
    for (int i = 0; i < 16; ++i) {
        int d = i * 4 + ty;
        tile[d][tx] = x[((size_t)(b * 512 + d0 + d)) * 4096 + n0 + tx];
    }
    __syncthreads();
#pragma unroll
    for (int i = 0; i < 16; ++i) {
        int n = i * 4 + ty;
        xt[((size_t)(b * 4096 + n0 + n)) * 512 + d0 + tx] = (bf16)tile[tx][n];
    }
}

// v_cm[b][c][m] = v_nm[b*4096+m][c]
__global__ __launch_bounds__(256) void transpose_v_kernel(
    const bf16* __restrict__ v_nm, bf16* __restrict__ v_cm)
{
    __shared__ float tile[64][65];
    int b = blockIdx.z;
    int m0 = blockIdx.x * 64;
    int c0 = blockIdx.y * 64;
    int tx = threadIdx.x & 63, ty = threadIdx.x >> 6;
#pragma unroll
    for (int i = 0; i < 16; ++i) {
        int m = i * 4 + ty;
        tile[m][tx] = (float)v_nm[((size_t)(b * 4096 + m0 + m)) * 256 + c0 + tx];
    }
    __syncthreads();
#pragma unroll
    for (int i = 0; i < 16; ++i) {
        int c = i * 4 + ty;
        v_cm[((size_t)(b * 256 + c0 + c)) * 4096 + m0 + tx] = (bf16)tile[tx][c];
    }
}

// ------------------------------ GEMM kernels -------------------------------

// x1t[row][col] = silu(bn1( sum_d xt[row][d] * w1b[col][d] ))
__global__ __launch_bounds__(256) void gemm1_kernel(
    const bf16* __restrict__ xt, const bf16* __restrict__ w1b,
    const float* __restrict__ bn1s, const float* __restrict__ bn1h,
    bf16* __restrict__ x1t)
{
    const bf16* A = xt + (size_t)(blockIdx.y * 128) * 512;
    const bf16* Bm = w1b + (size_t)(blockIdx.x * 128) * 512;
    f32x4 acc[4][4];
    gemm_core_lds(A, 512, Bm, 512, 512, acc);
    int wave = threadIdx.x >> 6;
    int lane = threadIdx.x & 63;
    int m0 = blockIdx.y * 128 + (wave >> 1) * 64;
    int n0 = blockIdx.x * 128 + (wave & 1) * 64;
    int lm = lane & 15, kq = lane >> 4;
#pragma unroll
    for (int i = 0; i < 4; ++i)
#pragma unroll
        for (int j = 0; j < 4; ++j)
#pragma unroll
            for (int r = 0; r < 4; ++r) {
                int row = m0 + i * 16 + kq * 4 + r;
                int col = n0 + j * 16 + lm;
                float h = bn1s[col] * acc[i][j][r] + bn1h[col];
                x1t[(size_t)row * 256 + col] = (bf16)silu_f(h);
            }
}

// projections: col<256 -> qp[.][col]; <512 -> ke[.][col-256];
//              <768 -> v_nm[.][col-512]; else ke[.][256+col-768]
__global__ __launch_bounds__(256) void gemm2_kernel(
    const bf16* __restrict__ x1t, const bf16* __restrict__ wqkve,
    const float* __restrict__ biasq,
    bf16* __restrict__ qp, bf16* __restrict__ ke, bf16* __restrict__ v_nm)
{
    const bf16* A = x1t + (size_t)(blockIdx.y * 128) * 256;
    const bf16* Bm = wqkve + (size_t)(blockIdx.x * 128) * 256;
    f32x4 acc[4][4];
    gemm_core_lds(A, 256, Bm, 256, 256, acc);
    int wave = threadIdx.x >> 6;
    int lane = threadIdx.x & 63;
    int m0 = blockIdx.y * 128 + (wave >> 1) * 64;
    int n0 = blockIdx.x * 128 + (wave & 1) * 64;
    int lm = lane & 15, kq = lane >> 4;
#pragma unroll
    for (int i = 0; i < 4; ++i)
#pragma unroll
        for (int j = 0; j < 4; ++j)
#pragma unroll
            for (int r = 0; r < 4; ++r) {
                int row = m0 + i * 16 + kq * 4 + r;
                int col = n0 + j * 16 + lm;
                bf16 val = (bf16)(acc[i][j][r] + biasq[col]);
                if (col < 256)       qp[(size_t)row * 512 + col] = val;
                else if (col < 512)  ke[(size_t)row * 512 + (col - 256)] = val;
                else if (col < 768)  v_nm[(size_t)row * 256 + (col - 512)] = val;
                else                 ke[(size_t)row * 512 + 256 + (col - 768)] = val;
            }
}

// P[bz][n][m] = qp[b,n,:] . ke[b,m,:]  (K=512), bf16 out, batched group of 4
__global__ __launch_bounds__(256) void gemm3b_kernel(
    const bf16* __restrict__ qp, const bf16* __restrict__ ke,
    bf16* __restrict__ P, int gbase)
{
    int bz = blockIdx.z;
    int b = gbase + bz;
    const bf16* A = qp + ((size_t)b * 4096 + blockIdx.y * 128) * 512;
    const bf16* Bm = ke + ((size_t)b * 4096 + blockIdx.x * 128) * 512;
    f32x4 acc[4][4];
    gemm_core_lds(A, 512, Bm, 512, 512, acc);
    int wave = threadIdx.x >> 6;
    int lane = threadIdx.x & 63;
    int m0 = (wave >> 1) * 64, n0 = (wave & 1) * 64;
    int lm = lane & 15, kq = lane >> 4;
    bf16* Pb = P + ((size_t)bz * 4096 + blockIdx.y * 128) * 4096 + blockIdx.x * 128;
#pragma unroll
    for (int i = 0; i < 4; ++i)
#pragma unroll
        for (int j = 0; j < 4; ++j)
#pragma unroll
            for (int r = 0; r < 4; ++r)
                Pb[(size_t)(m0 + i * 16 + kq * 4 + r) * 4096 + n0 + j * 16 + lm] =
                    (bf16)acc[i][j][r];
}

// in-place row softmax on bf16 P (16384 rows x 4096)
__global__ __launch_bounds__(256) void softmax_b_kernel(bf16* __restrict__ P)
{
    __shared__ float red[4];
    bf16* p = P + (size_t)blockIdx.x * 4096;
    int t = threadIdx.x;
    int lane = t & 63, wid = t >> 6;
    float v[16];
    bf16x8 h0 = *(const bf16x8*)(p + t * 16);
    bf16x8 h1 = *(const bf16x8*)(p + t * 16 + 8);
#pragma unroll
    for (int i = 0; i < 8; ++i) { v[i] = (float)h0[i]; v[8 + i] = (float)h1[i]; }
    float mx = -1e30f;
#pragma unroll
    for (int i = 0; i < 16; ++i) mx = fmaxf(mx, v[i]);
#pragma unroll
    for (int o = 32; o > 0; o >>= 1) mx = fmaxf(mx, __shfl_down(mx, o));
    if (lane == 0) red[wid] = mx;
    __syncthreads();
    mx = fmaxf(fmaxf(red[0], red[1]), fmaxf(red[2], red[3]));
    __syncthreads();
    float sum = 0.f;
#pragma unroll
    for (int i = 0; i < 16; ++i) {
        v[i] = __expf(v[i] - mx);
        sum += v[i];
    }
#pragma unroll
    for (int o = 32; o > 0; o >>= 1) sum += __shfl_down(sum, o);
    if (lane == 0) red[wid] = sum;
    __syncthreads();
    float inv = 1.f / (red[0] + red[1] + red[2] + red[3]);
    bf16x8 o0, o1;
#pragma unroll
    for (int i = 0; i < 8; ++i) {
        o0[i] = (bf16)(v[i] * inv);
        o1[i] = (bf16)(v[8 + i] * inv);
    }
    *(bf16x8*)(p + t * 16) = o0;
    *(bf16x8*)(p + t * 16 + 8) = o1;
}

// out_t[(gbase+bz)*4096+n][c] = sum_m P[bz][n][m] * v_cm[gbase+bz][c][m]
__global__ __launch_bounds__(256) void gemm4b_kernel(
    const bf16* __restrict__ P, const bf16* __restrict__ v_cm,
    bf16* __restrict__ out_t, int gbase)
{
    int bz = blockIdx.z;
    int b = gbase + bz;
    const bf16* A = P + ((size_t)bz * 4096 + blockIdx.y * 128) * 4096;
    const bf16* Bm = v_cm + ((size_t)b * 256 + blockIdx.x * 128) * 4096;
    f32x4 acc[4][4];
    gemm_core_lds(A, 4096, Bm, 4096, 4096, acc);
    int wave = threadIdx.x >> 6;
    int lane = threadIdx.x & 63;
    int m0 = (wave >> 1) * 64, n0 = (wave & 1) * 64;
    int lm = lane & 15, kq = lane >> 4;
    bf16* ob = out_t + ((size_t)b * 4096 + blockIdx.y * 128) * 256 + blockIdx.x * 128;
#pragma unroll
    for (int i = 0; i < 4; ++i)
#pragma unroll
        for (int j = 0; j < 4; ++j)
#pragma unroll
            for (int r = 0; r < 4; ++r)
                ob[(size_t)(m0 + i * 16 + kq * 4 + r) * 256 + n0 + j * 16 + lm] =
                    (bf16)acc[i][j][r];
}

// d_out[b][d][n] = x[b][d][n] + silu(bn2( sum_c w2b[d][c]*out_t[b*4096+n][c] ))
__global__ __launch_bounds__(256) void gemm5_kernel(
    const bf16* __restrict__ w2b, const bf16* __restrict__ out_t,
    const float* __restrict__ bn2s, const float* __restrict__ bn2h,
    const float* __restrict__ x, float* __restrict__ out)
{
    int b = blockIdx.z;
    const bf16* A = w2b + (size_t)(blockIdx.y * 128) * 256;
    const bf16* Bm = out_t + ((size_t)b * 4096 + blockIdx.x * 128) * 256;
    f32x4 acc[4][4];
    gemm_core_lds(A, 256, Bm, 256, 256, acc);
    int wave = threadIdx.x >> 6;
    int lane = threadIdx.x & 63;
    int m0 = blockIdx.y * 128 + (wave >> 1) * 64;   // d (512)
    int n0 = blockIdx.x * 128 + (wave & 1) * 64;    // n (4096)
    int lm = lane & 15, kq = lane >> 4;
#pragma unroll
    for (int i = 0; i < 4; ++i)
#pragma unroll
        for (int j = 0; j < 4; ++j)
#pragma unroll
            for (int r = 0; r < 4; ++r) {
                int d = m0 + i * 16 + kq * 4 + r;
                int n = n0 + j * 16 + lm;
                float h = bn2s[d] * acc[i][j][r] + bn2h[d];
                size_t gi = ((size_t)(b * 512 + d)) * 4096 + n;
                out[gi] = x[gi] + silu_f(h);
            }
}

// ------------------------------- launcher ----------------------------------

extern "C" void kernel_launch(void* const* d_in, const int* in_sizes, int n_in,
                              void* d_out, int out_size, void* d_ws, size_t ws_size,
                              hipStream_t stream)
{
    (void)in_sizes; (void)n_in; (void)out_size; (void)ws_size;
    const float* x     = (const float*)d_in[0];
    const float* cv1_w = (const float*)d_in[1];
    const float* bn1_g = (const float*)d_in[2];
    const float* bn1_b = (const float*)d_in[3];
    const float* bn1_m = (const float*)d_in[4];
    const float* bn1_v = (const float*)d_in[5];
    const float* q_w   = (const float*)d_in[6];
    const float* q_b   = (const float*)d_in[7];
    const float* k_w   = (const float*)d_in[8];
    const float* k_b   = (const float*)d_in[9];
    const float* v_w   = (const float*)d_in[10];
    const float* v_b   = (const float*)d_in[11];
    const float* e_w   = (const float*)d_in[12];
    const float* e_b   = (const float*)d_in[13];
    const float* rel_h = (const float*)d_in[14];
    const float* rel_w = (const float*)d_in[15];
    const float* cv2_w = (const float*)d_in[16];
    const float* bn2_g = (const float*)d_in[17];
    const float* bn2_b = (const float*)d_in[18];
    const float* bn2_m = (const float*)d_in[19];
    const float* bn2_v = (const float*)d_in[20];
    float* out = (float*)d_out;

    char* ws = (char*)d_ws;
    // P_grp region (128 MB) also hosts xt/x1t/v_nm (all dead before attention)
    bf16* P     = (bf16*)(ws + 0);            // 128 MB [4][4096][4096]
    bf16* xt    = (bf16*)(ws + 0);            //  32 MB overlay
    bf16* x1t   = (bf16*)(ws + 33554432);     //  16 MB overlay
    bf16* v_nm  = (bf16*)(ws + 50331648);     //  16 MB overlay
    bf16* qp    = (bf16*)(ws + 134217728);    //  32 MB [32768][512]
    bf16* ke    = (bf16*)(ws + 167772160);    //  32 MB [32768][512]
    bf16* v_cm  = (bf16*)(ws + 201326592);    //  16 MB [8][256][4096]
    bf16* out_t = (bf16*)(ws + 218103808);    //  16 MB [32768][256]
    bf16* w1b   = (bf16*)(ws + 234881024);    // 256 KB
    bf16* wqkve = (bf16*)(ws + 235143168);    // 512 KB
    bf16* w2b   = (bf16*)(ws + 235667456);    // 256 KB
    float* biasq= (float*)(ws + 235929600);   //   4 KB
    float* bn1s = (float*)(ws + 235933696);
    float* bn1h = (float*)(ws + 235934720);
    float* bn2s = (float*)(ws + 235935744);
    float* bn2h = (float*)(ws + 235937792);

    prep_misc_kernel<<<2055, 256, 0, stream>>>(
        cv1_w, q_w, q_b, k_w, k_b, v_w, v_b, e_w, e_b, cv2_w,
        bn1_g, bn1_b, bn1_m, bn1_v, bn2_g, bn2_b, bn2_m, bn2_v,
        w1b, wqkve, w2b, biasq, bn1s, bn1h, bn2s, bn2h);
    transpose_x_kernel<<<dim3(64, 8, 8), 256, 0, stream>>>(x, xt);
    gemm1_kernel<<<dim3(2, 256), 256, 0, stream>>>(xt, w1b, bn1s, bn1h, x1t);
    gemm2_kernel<<<dim3(8, 256), 256, 0, stream>>>(x1t, wqkve, biasq, qp, ke, v_nm);
    pos_prep_kernel<<<4096, 256, 0, stream>>>(rel_h, rel_w, qp);
    transpose_v_kernel<<<dim3(64, 4, 8), 256, 0, stream>>>(v_nm, v_cm);
    for (int g = 0; g < 2; ++g) {
        gemm3b_kernel<<<dim3(32, 32, 4), 256, 0, stream>>>(qp, ke, P, g * 4);
        softmax_b_kernel<<<16384, 256, 0, stream>>>(P);
        gemm4b_kernel<<<dim3(2, 32, 4), 256, 0, stream>>>(P, v_cm, out_t, g * 4);
    }
    gemm5_kernel<<<dim3(32, 4, 8), 256, 0, stream>>>(w2b, out_t, bn2s, bn2h, x, out);
}

// Round 4
// 662.152 us; speedup vs baseline: 3.0450x; 1.1085x over previous
//
#include <hip/hip_runtime.h>

// ---------------------------------------------------------------------------
// ExtraPositionPromptSABottleneck on MI355X (gfx950)
// B=8, DIMS=512, C=256, H=W=64, N=4096.
//
// Round 4:
//  - LDS XOR swizzle in the GEMM core: store-side fetch swizzle
//    (kblock ^= (row>>1)&3) keeps global_load_lds contiguous-dest; read
//    offset is per-lane constant kq^((lm>>1)&3). Fixes the measured 8-way
//    bank conflict (8.4M cycles/dispatch in round 3).
//  - Softmax kernel eliminated: gemm3b epilogue stores exp(S-8) bf16 and
//    atomically accumulates fp32 row sums (block-level LDS reduce first);
//    gemm4b epilogue multiplies by 1/rowsum. Saves a full 256 MB/group pass.
// ---------------------------------------------------------------------------

typedef __bf16 bf16;
typedef __attribute__((ext_vector_type(8))) __bf16 bf16x8;
typedef __attribute__((ext_vector_type(4))) float f32x4;

__device__ __forceinline__ float silu_f(float x) { return x / (1.f + __expf(-x)); }

__device__ __forceinline__ void zero_acc(f32x4 (&acc)[4][4])
{
#pragma unroll
    for (int i = 0; i < 4; ++i)
#pragma unroll
        for (int j = 0; j < 4; ++j)
            acc[i][j] = (f32x4){0.f, 0.f, 0.f, 0.f};
}

// ---- LDS-staged GEMM core: block 256 thr, tile 128x128, BK=32
__device__ __forceinline__ void load_lds16(const bf16* g, bf16* l)
{
    __builtin_amdgcn_global_load_lds(
        (const __attribute__((address_space(1))) unsigned int*)g,
        (__attribute__((address_space(3))) unsigned int*)l, 16, 0, 0);
}

// A: block's 128 rows, k-contig stride lda. B: block's 128 "cols", stride ldb.
// LDS slot (row, kb) holds global (row, kb ^ ((row>>1)&3)) -- XOR swizzle.
__device__ __forceinline__ void gemm_core_lds(
    const bf16* __restrict__ A, int lda,
    const bf16* __restrict__ B, int ldb,
    int K, f32x4 (&acc)[4][4])
{
    __shared__ bf16 As[128 * 32];
    __shared__ bf16 Bs[128 * 32];
    const int tid = threadIdx.x;
    const int wave = tid >> 6;
    const int lane = tid & 63;
    const int lm = lane & 15;
    const int kq = lane >> 4;
    const int m0 = (wave >> 1) * 64;
    const int n0 = (wave & 1) * 64;
    // staging: each thread supplies 16B per round; 2 rounds per matrix.
    const int srow = tid >> 2;                              // rows 0..63, +64
    const int skoff = (((tid & 3) ^ ((tid >> 3) & 3))) * 8; // swizzled k-block
    const int krd = (kq ^ ((lm >> 1) & 3)) * 8;             // read-side offset
    bf16* lA = As + tid * 8;            // LDS dest = wave_base + lane*16B
    bf16* lB = Bs + tid * 8;
    zero_acc(acc);
    for (int k0 = 0; k0 < K; k0 += 32) {
        const bf16* ga = A + (size_t)srow * lda + k0 + skoff;
        const bf16* gb = B + (size_t)srow * ldb + k0 + skoff;
        load_lds16(ga, lA);
        load_lds16(ga + (size_t)64 * lda, lA + 64 * 32);
        load_lds16(gb, lB);
        load_lds16(gb + (size_t)64 * ldb, lB + 64 * 32);
        __syncthreads();
        bf16x8 av[4], bv[4];
#pragma unroll
        for (int t = 0; t < 4; ++t)
            av[t] = *(const bf16x8*)(As + (m0 + t * 16 + lm) * 32 + krd);
#pragma unroll
        for (int t = 0; t < 4; ++t)
            bv[t] = *(const bf16x8*)(Bs + (n0 + t * 16 + lm) * 32 + krd);
#pragma unroll
        for (int i = 0; i < 4; ++i)
#pragma unroll
            for (int j = 0; j < 4; ++j)
                acc[i][j] = __builtin_amdgcn_mfma_f32_16x16x32_bf16(
                    av[i], bv[j], acc[i][j], 0, 0, 0);
        __syncthreads();
    }
}

// ------------------------------ prep kernels -------------------------------

__global__ __launch_bounds__(256) void prep_misc_kernel(
    const float* __restrict__ cv1_w,
    const float* __restrict__ qw, const float* __restrict__ qb,
    const float* __restrict__ kw, const float* __restrict__ kb,
    const float* __restrict__ vw, const float* __restrict__ vb,
    const float* __restrict__ ew, const float* __restrict__ eb,
    const float* __restrict__ cv2_w,
    const float* __restrict__ g1, const float* __restrict__ b1,
    const float* __restrict__ m1, const float* __restrict__ v1,
    const float* __restrict__ g2, const float* __restrict__ b2,
    const float* __restrict__ m2, const float* __restrict__ v2,
    bf16* __restrict__ w1b, bf16* __restrict__ wqkve, bf16* __restrict__ w2b,
    float* __restrict__ biasq,
    float* __restrict__ bn1s, float* __restrict__ bn1h,
    float* __restrict__ bn2s, float* __restrict__ bn2h)
{
    int idx = blockIdx.x * 256 + threadIdx.x;
    if (idx < 131072) { w1b[idx] = (bf16)cv1_w[idx]; return; }
    idx -= 131072;
    if (idx < 262144) {
        int j = idx >> 8, c = idx & 255;
        int p = j >> 8, r = j & 255;
        const float* w = (p == 0) ? qw : (p == 1) ? kw : (p == 2) ? vw : ew;
        wqkve[idx] = (bf16)w[r * 256 + c];
        return;
    }
    idx -= 262144;
    if (idx < 131072) { w2b[idx] = (bf16)cv2_w[idx]; return; }
    idx -= 131072;
    if (idx < 1024) {
        int p = idx >> 8, r = idx & 255;
        const float* bb = (p == 0) ? qb : (p == 1) ? kb : (p == 2) ? vb : eb;
        biasq[idx] = bb[r];
        return;
    }
    idx -= 1024;
    if (idx < 256) {
        float s = g1[idx] * rsqrtf(v1[idx] + 1e-5f);
        bn1s[idx] = s;
        bn1h[idx] = b1[idx] - m1[idx] * s;
        return;
    }
    idx -= 256;
    if (idx < 512) {
        float s = g2[idx] * rsqrtf(v2[idx] + 1e-5f);
        bn2s[idx] = s;
        bn2h[idx] = b2[idx] - m2[idx] * s;
        return;
    }
}

__global__ __launch_bounds__(256) void zero_lsum_kernel(float* __restrict__ p)
{
    p[blockIdx.x * 256 + threadIdx.x] = 0.f;
}

// qp[b*4096+n][256+c] = rel_h[c][h] + rel_w[c][w] for all b (pos half of qp)
__global__ __launch_bounds__(256) void pos_prep_kernel(
    const float* __restrict__ rel_h, const float* __restrict__ rel_w,
    bf16* __restrict__ qp)
{
    int n = blockIdx.x;
    int c = threadIdx.x;
    int h = n >> 6, w = n & 63;
    bf16 val = (bf16)(rel_h[c * 64 + h] + rel_w[c * 64 + w]);
#pragma unroll
    for (int b = 0; b < 8; ++b)
        qp[((size_t)(b * 4096 + n)) * 512 + 256 + c] = val;
}

// xt[b*4096+n][d] = (bf16) x[b][d][n]
__global__ __launch_bounds__(256) void transpose_x_kernel(
    const float* __restrict__ x, bf16* __restrict__ xt)
{
    __shared__ float tile[64][65];
    int b = blockIdx.z;
    int n0 = blockIdx.x * 64;
    int d0 = blockIdx.y * 64;
    int tx = threadIdx.x & 63, ty = threadIdx.x >> 6;
#pragma unroll
    for (int i = 0; i < 16; ++i) {
        int d = i * 4 + ty;
        tile[d][tx] = x[((size_t)(b * 512 + d0 + d)) * 4096 + n0 + tx];
    }
    __syncthreads();
#pragma unroll
    for (int i = 0; i < 16; ++i) {
        int n = i * 4 + ty;
        xt[((size_t)(b * 4096 + n0 + n)) * 512 + d0 + tx] = (bf16)tile[tx][n];
    }
}

// v_cm[b][c][m] = v_nm[b*4096+m][c]
__global__ __launch_bounds__(256) void transpose_v_kernel(
    const bf16* __restrict__ v_nm, bf16* __restrict__ v_cm)
{
    __shared__ float tile[64][65];
    int b = blockIdx.z;
    int m0 = blockIdx.x * 64;
    int c0 = blockIdx.y * 64;
    int tx = threadIdx.x & 63, ty = threadIdx.x >> 6;
#pragma unroll
    for (int i = 0; i < 16; ++i) {
        int m = i * 4 + ty;
        tile[m][tx] = (float)v_nm[((size_t)(b * 4096 + m0 + m)) * 256 + c0 + tx];
    }
    __syncthreads();
#pragma unroll
    for (int i = 0; i < 16; ++i) {
        int c = i * 4 + ty;
        v_cm[((size_t)(b * 256 + c0 + c)) * 4096 + m0 + tx] = (bf16)tile[tx][c];
    }
}

// ------------------------------ GEMM kernels -------------------------------

// x1t[row][col] = silu(bn1( sum_d xt[row][d] * w1b[col][d] ))
__global__ __launch_bounds__(256) void gemm1_kernel(
    const bf16* __restrict__ xt, const bf16* __restrict__ w1b,
    const float* __restrict__ bn1s, const float* __restrict__ bn1h,
    bf16* __restrict__ x1t)
{
    const bf16* A = xt + (size_t)(blockIdx.y * 128) * 512;
    const bf16* Bm = w1b + (size_t)(blockIdx.x * 128) * 512;
    f32x4 acc[4][4];
    gemm_core_lds(A, 512, Bm, 512, 512, acc);
    int wave = threadIdx.x >> 6;
    int lane = threadIdx.x & 63;
    int m0 = blockIdx.y * 128 + (wave >> 1) * 64;
    int n0 = blockIdx.x * 128 + (wave & 1) * 64;
    int lm = lane & 15, kq = lane >> 4;
#pragma unroll
    for (int i = 0; i < 4; ++i)
#pragma unroll
        for (int j = 0; j < 4; ++j)
#pragma unroll
            for (int r = 0; r < 4; ++r) {
                int row = m0 + i * 16 + kq * 4 + r;
                int col = n0 + j * 16 + lm;
                float h = bn1s[col] * acc[i][j][r] + bn1h[col];
                x1t[(size_t)row * 256 + col] = (bf16)silu_f(h);
            }
}

// projections: col<256 -> qp[.][col]; <512 -> ke[.][col-256];
//              <768 -> v_nm[.][col-512]; else ke[.][256+col-768]
__global__ __launch_bounds__(256) void gemm2_kernel(
    const bf16* __restrict__ x1t, const bf16* __restrict__ wqkve,
    const float* __restrict__ biasq,
    bf16* __restrict__ qp, bf16* __restrict__ ke, bf16* __restrict__ v_nm)
{
    const bf16* A = x1t + (size_t)(blockIdx.y * 128) * 256;
    const bf16* Bm = wqkve + (size_t)(blockIdx.x * 128) * 256;
    f32x4 acc[4][4];
    gemm_core_lds(A, 256, Bm, 256, 256, acc);
    int wave = threadIdx.x >> 6;
    int lane = threadIdx.x & 63;
    int m0 = blockIdx.y * 128 + (wave >> 1) * 64;
    int n0 = blockIdx.x * 128 + (wave & 1) * 64;
    int lm = lane & 15, kq = lane >> 4;
#pragma unroll
    for (int i = 0; i < 4; ++i)
#pragma unroll
        for (int j = 0; j < 4; ++j)
#pragma unroll
            for (int r = 0; r < 4; ++r) {
                int row = m0 + i * 16 + kq * 4 + r;
                int col = n0 + j * 16 + lm;
                bf16 val = (bf16)(acc[i][j][r] + biasq[col]);
                if (col < 256)       qp[(size_t)row * 512 + col] = val;
                else if (col < 512)  ke[(size_t)row * 512 + (col - 256)] = val;
                else if (col < 768)  v_nm[(size_t)row * 256 + (col - 512)] = val;
                else                 ke[(size_t)row * 512 + 256 + (col - 768)] = val;
            }
}

// P[bz][n][m] = exp(qp[b,n,:].ke[b,m,:] - 8), bf16; row sums -> lsum[bz][n]
__global__ __launch_bounds__(256) void gemm3b_kernel(
    const bf16* __restrict__ qp, const bf16* __restrict__ ke,
    bf16* __restrict__ P, float* __restrict__ lsum, int gbase)
{
    __shared__ float rs[128];
    int bz = blockIdx.z;
    int b = gbase + bz;
    const bf16* A = qp + ((size_t)b * 4096 + blockIdx.y * 128) * 512;
    const bf16* Bm = ke + ((size_t)b * 4096 + blockIdx.x * 128) * 512;
    f32x4 acc[4][4];
    gemm_core_lds(A, 512, Bm, 512, 512, acc);
    int tid = threadIdx.x;
    int wave = tid >> 6;
    int lane = tid & 63;
    int m0 = (wave >> 1) * 64, n0 = (wave & 1) * 64;
    int lm = lane & 15, kq = lane >> 4;
    if (tid < 128) rs[tid] = 0.f;
    __syncthreads();
    // exp in place + per-lane row partials (sum over this lane's 4 cols)
    float ps[4][4];
#pragma unroll
    for (int i = 0; i < 4; ++i)
#pragma unroll
        for (int r = 0; r < 4; ++r) {
            float s = 0.f;
#pragma unroll
            for (int j = 0; j < 4; ++j) {
                float e = __expf(acc[i][j][r] - 8.f);
                acc[i][j][r] = e;
                s += e;
            }
            ps[i][r] = s;
        }
    // butterfly over the 16-lane lm group (covers the wave's 64 cols)
#pragma unroll
    for (int msk = 1; msk < 16; msk <<= 1)
#pragma unroll
        for (int i = 0; i < 4; ++i)
#pragma unroll
            for (int r = 0; r < 4; ++r)
                ps[i][r] += __shfl_xor(ps[i][r], msk);
    if (lm == 0) {
#pragma unroll
        for (int i = 0; i < 4; ++i)
#pragma unroll
            for (int r = 0; r < 4; ++r)
                atomicAdd(&rs[m0 + i * 16 + kq * 4 + r], ps[i][r]);
    }
    // store exp(S) tile
    bf16* Pb = P + ((size_t)bz * 4096 + blockIdx.y * 128) * 4096 + blockIdx.x * 128;
#pragma unroll
    for (int i = 0; i < 4; ++i)
#pragma unroll
        for (int j = 0; j < 4; ++j)
#pragma unroll
            for (int r = 0; r < 4; ++r)
                Pb[(size_t)(m0 + i * 16 + kq * 4 + r) * 4096 + n0 + j * 16 + lm] =
                    (bf16)acc[i][j][r];
    __syncthreads();
    if (tid < 128)
        atomicAdd(&lsum[(size_t)bz * 4096 + blockIdx.y * 128 + tid], rs[tid]);
}

// out_t[(gbase+bz)*4096+n][c] = (1/lsum[bz][n]) * sum_m P[bz][n][m]*v_cm[b][c][m]
__global__ __launch_bounds__(256) void gemm4b_kernel(
    const bf16* __restrict__ P, const bf16* __restrict__ v_cm,
    const float* __restrict__ lsum,
    bf16* __restrict__ out_t, int gbase)
{
    int bz = blockIdx.z;
    int b = gbase + bz;
    const bf16* A = P + ((size_t)bz * 4096 + blockIdx.y * 128) * 4096;
    const bf16* Bm = v_cm + ((size_t)b * 256 + blockIdx.x * 128) * 4096;
    f32x4 acc[4][4];
    gemm_core_lds(A, 4096, Bm, 4096, 4096, acc);
    int wave = threadIdx.x >> 6;
    int lane = threadIdx.x & 63;
    int m0 = (wave >> 1) * 64, n0 = (wave & 1) * 64;
    int lm = lane & 15, kq = lane >> 4;
    const float* ls = lsum + (size_t)bz * 4096 + blockIdx.y * 128;
    bf16* ob = out_t + ((size_t)b * 4096 + blockIdx.y * 128) * 256 + blockIdx.x * 128;
#pragma unroll
    for (int i = 0; i < 4; ++i)
#pragma unroll
        for (int r = 0; r < 4; ++r) {
            float inv = 1.f / ls[m0 + i * 16 + kq * 4 + r];
#pragma unroll
            for (int j = 0; j < 4; ++j)
                ob[(size_t)(m0 + i * 16 + kq * 4 + r) * 256 + n0 + j * 16 + lm] =
                    (bf16)(acc[i][j][r] * inv);
        }
}

// d_out[b][d][n] = x[b][d][n] + silu(bn2( sum_c w2b[d][c]*out_t[b*4096+n][c] ))
__global__ __launch_bounds__(256) void gemm5_kernel(
    const bf16* __restrict__ w2b, const bf16* __restrict__ out_t,
    const float* __restrict__ bn2s, const float* __restrict__ bn2h,
    const float* __restrict__ x, float* __restrict__ out)
{
    int b = blockIdx.z;
    const bf16* A = w2b + (size_t)(blockIdx.y * 128) * 256;
    const bf16* Bm = out_t + ((size_t)b * 4096 + blockIdx.x * 128) * 256;
    f32x4 acc[4][4];
    gemm_core_lds(A, 256, Bm, 256, 256, acc);
    int wave = threadIdx.x >> 6;
    int lane = threadIdx.x & 63;
    int m0 = blockIdx.y * 128 + (wave >> 1) * 64;   // d (512)
    int n0 = blockIdx.x * 128 + (wave & 1) * 64;    // n (4096)
    int lm = lane & 15, kq = lane >> 4;
#pragma unroll
    for (int i = 0; i < 4; ++i)
#pragma unroll
        for (int j = 0; j < 4; ++j)
#pragma unroll
            for (int r = 0; r < 4; ++r) {
                int d = m0 + i * 16 + kq * 4 + r;
                int n = n0 + j * 16 + lm;
                float h = bn2s[d] * acc[i][j][r] + bn2h[d];
                size_t gi = ((size_t)(b * 512 + d)) * 4096 + n;
                out[gi] = x[gi] + silu_f(h);
            }
}

// ------------------------------- launcher ----------------------------------

extern "C" void kernel_launch(void* const* d_in, const int* in_sizes, int n_in,
                              void* d_out, int out_size, void* d_ws, size_t ws_size,
                              hipStream_t stream)
{
    (void)in_sizes; (void)n_in; (void)out_size; (void)ws_size;
    const float* x     = (const float*)d_in[0];
    const float* cv1_w = (const float*)d_in[1];
    const float* bn1_g = (const float*)d_in[2];
    const float* bn1_b = (const float*)d_in[3];
    const float* bn1_m = (const float*)d_in[4];
    const float* bn1_v = (const float*)d_in[5];
    const float* q_w   = (const float*)d_in[6];
    const float* q_b   = (const float*)d_in[7];
    const float* k_w   = (const float*)d_in[8];
    const float* k_b   = (const float*)d_in[9];
    const float* v_w   = (const float*)d_in[10];
    const float* v_b   = (const float*)d_in[11];
    const float* e_w   = (const float*)d_in[12];
    const float* e_b   = (const float*)d_in[13];
    const float* rel_h = (const float*)d_in[14];
    const float* rel_w = (const float*)d_in[15];
    const float* cv2_w = (const float*)d_in[16];
    const float* bn2_g = (const float*)d_in[17];
    const float* bn2_b = (const float*)d_in[18];
    const float* bn2_m = (const float*)d_in[19];
    const float* bn2_v = (const float*)d_in[20];
    float* out = (float*)d_out;

    char* ws = (char*)d_ws;
    // P_grp region (128 MB) also hosts xt/x1t/v_nm (all dead before attention)
    bf16* P     = (bf16*)(ws + 0);            // 128 MB [4][4096][4096]
    bf16* xt    = (bf16*)(ws + 0);            //  32 MB overlay
    bf16* x1t   = (bf16*)(ws + 33554432);     //  16 MB overlay
    bf16* v_nm  = (bf16*)(ws + 50331648);     //  16 MB overlay
    bf16* qp    = (bf16*)(ws + 134217728);    //  32 MB [32768][512]
    bf16* ke    = (bf16*)(ws + 167772160);    //  32 MB [32768][512]
    bf16* v_cm  = (bf16*)(ws + 201326592);    //  16 MB [8][256][4096]
    bf16* out_t = (bf16*)(ws + 218103808);    //  16 MB [32768][256]
    bf16* w1b   = (bf16*)(ws + 234881024);    // 256 KB
    bf16* wqkve = (bf16*)(ws + 235143168);    // 512 KB
    bf16* w2b   = (bf16*)(ws + 235667456);    // 256 KB
    float* biasq= (float*)(ws + 235929600);   //   4 KB
    float* bn1s = (float*)(ws + 235933696);
    float* bn1h = (float*)(ws + 235934720);
    float* bn2s = (float*)(ws + 235935744);
    float* bn2h = (float*)(ws + 235937792);
    float* lsum = (float*)(ws + 235941888);   // 128 KB [2][4][4096] fp32

    prep_misc_kernel<<<2055, 256, 0, stream>>>(
        cv1_w, q_w, q_b, k_w, k_b, v_w, v_b, e_w, e_b, cv2_w,
        bn1_g, bn1_b, bn1_m, bn1_v, bn2_g, bn2_b, bn2_m, bn2_v,
        w1b, wqkve, w2b, biasq, bn1s, bn1h, bn2s, bn2h);
    zero_lsum_kernel<<<128, 256, 0, stream>>>(lsum);
    transpose_x_kernel<<<dim3(64, 8, 8), 256, 0, stream>>>(x, xt);
    gemm1_kernel<<<dim3(2, 256), 256, 0, stream>>>(xt, w1b, bn1s, bn1h, x1t);
    gemm2_kernel<<<dim3(8, 256), 256, 0, stream>>>(x1t, wqkve, biasq, qp, ke, v_nm);
    pos_prep_kernel<<<4096, 256, 0, stream>>>(rel_h, rel_w, qp);
    transpose_v_kernel<<<dim3(64, 4, 8), 256, 0, stream>>>(v_nm, v_cm);
    for (int g = 0; g < 2; ++g) {
        float* ls = lsum + (size_t)g * 4 * 4096;
        gemm3b_kernel<<<dim3(32, 32, 4), 256, 0, stream>>>(qp, ke, P, ls, g * 4);
        gemm4b_kernel<<<dim3(2, 32, 4), 256, 0, stream>>>(P, v_cm, ls, out_t, g * 4);
    }
    gemm5_kernel<<<dim3(32, 4, 8), 256, 0, stream>>>(w2b, out_t, bn2s, bn2h, x, out);
}